// Round 1
// baseline (331.444 us; speedup 1.0000x reference)
//
#include <hip/hip_runtime.h>
#include <math.h>

#define DM 512
#define NH 8
#define DH 64
#define SEQ 512
#define BATCH 8
#define MR 1023          // distinct relative offsets: 2*SEQ-1
#define PE_OFF 4489      // pe row for dd=0: (0-511)+5000

typedef float4 f4;

__device__ __forceinline__ float dot4(f4 a, f4 b, float acc) {
    acc = fmaf(a.x, b.x, acc);
    acc = fmaf(a.y, b.y, acc);
    acc = fmaf(a.z, b.z, acc);
    acc = fmaf(a.w, b.w, acc);
    return acc;
}

// ---------------------------------------------------------------------------
// C = A[M,512] @ W[512,512]^T (+bias[+bias2]) with 64x64 output tiles.
// MODE 0: scatter to q/k/v layout [B,H,S,dh]   (bias2 = u for the q proj)
// MODE 1: Rm[h][dd][dh], guard dd < 1023, no bias
// MODE 2: plain row-major [M,512] + bias       (output projection)
// ---------------------------------------------------------------------------
template<int MODE>
__global__ __launch_bounds__(256) void gemm_kernel(
    const float* __restrict__ A, const float* __restrict__ W,
    const float* __restrict__ bias, const float* __restrict__ bias2,
    float* __restrict__ C)
{
    __shared__ float As[16][68];   // [k][m], padded
    __shared__ float Bs[16][68];   // [k][n], padded

    const int tid = threadIdx.x;
    const int tx = tid & 15, ty = tid >> 4;
    const int m0 = blockIdx.y << 6;
    const int n0 = blockIdx.x << 6;
    const int lr = tid >> 2;          // 0..63  (row within tile for loads)
    const int lc = (tid & 3) << 2;    // k-quad for loads

    float acc[4][4] = {};

    for (int k0 = 0; k0 < DM; k0 += 16) {
        f4 av = *(const f4*)&A[(size_t)(m0 + lr) * DM + k0 + lc];
        f4 wv = *(const f4*)&W[(size_t)(n0 + lr) * DM + k0 + lc];
        if (k0) __syncthreads();
        As[lc + 0][lr] = av.x; As[lc + 1][lr] = av.y;
        As[lc + 2][lr] = av.z; As[lc + 3][lr] = av.w;
        Bs[lc + 0][lr] = wv.x; Bs[lc + 1][lr] = wv.y;
        Bs[lc + 2][lr] = wv.z; Bs[lc + 3][lr] = wv.w;
        __syncthreads();
#pragma unroll
        for (int kk = 0; kk < 16; ++kk) {
            f4 a = *(const f4*)&As[kk][ty << 2];
            f4 b = *(const f4*)&Bs[kk][tx << 2];
            float ar[4] = {a.x, a.y, a.z, a.w};
            float br[4] = {b.x, b.y, b.z, b.w};
#pragma unroll
            for (int i = 0; i < 4; ++i)
#pragma unroll
                for (int j = 0; j < 4; ++j)
                    acc[i][j] = fmaf(ar[i], br[j], acc[i][j]);
        }
    }

    float bv[4] = {0.f, 0.f, 0.f, 0.f};
    if (MODE != 1) {
#pragma unroll
        for (int j = 0; j < 4; ++j) {
            const int n = n0 + (tx << 2) + j;
            float t = bias ? bias[n] : 0.f;
            if (MODE == 0 && bias2) t += bias2[n];
            bv[j] = t;
        }
    }

    if (MODE == 0) {
        const int b = m0 >> 9, h = n0 >> 6;
#pragma unroll
        for (int i = 0; i < 4; ++i) {
            const int s = (m0 & 511) + (ty << 2) + i;
            f4 o = {acc[i][0] + bv[0], acc[i][1] + bv[1],
                    acc[i][2] + bv[2], acc[i][3] + bv[3]};
            *(f4*)&C[(((size_t)(b * NH + h) * SEQ + s) << 6) + (tx << 2)] = o;
        }
    } else if (MODE == 1) {
        const int h = n0 >> 6;
#pragma unroll
        for (int i = 0; i < 4; ++i) {
            const int dd = m0 + (ty << 2) + i;
            if (dd < MR) {
                f4 o = {acc[i][0], acc[i][1], acc[i][2], acc[i][3]};
                *(f4*)&C[((((size_t)h << 10) + dd) << 6) + (tx << 2)] = o;
            }
        }
    } else {
#pragma unroll
        for (int i = 0; i < 4; ++i) {
            const int m = m0 + (ty << 2) + i;
            f4 o = {acc[i][0] + bv[0], acc[i][1] + bv[1],
                    acc[i][2] + bv[2], acc[i][3] + bv[3]};
            *(f4*)&C[(size_t)m * DM + n0 + (tx << 2)] = o;
        }
    }
}

// rcorr[h][dd] = sum_d (v_bias[h,d] - u[h,d]) * Rm[h][dd][d]
__global__ __launch_bounds__(64) void corr_kernel(
    const float* __restrict__ Rm, const float* __restrict__ u,
    const float* __restrict__ vb, float* __restrict__ rc)
{
    const int h = blockIdx.y;
    const int dd = (blockIdx.x << 6) + threadIdx.x;
    float s = 0.f;
    if (dd < MR) {
        const float* r  = Rm + ((((size_t)h << 10) + dd) << 6);
        const float* uu = u + h * DH;
        const float* vv = vb + h * DH;
        for (int d = 0; d < DH; ++d) s = fmaf(vv[d] - uu[d], r[d], s);
    }
    rc[((size_t)h << 10) + dd] = s;
}

// ---------------------------------------------------------------------------
// Flash attention with relative position term.
// Block: 256 threads, one (b, h, 64-row i-tile). j-tiles of 32.
// score[i][j] = 0.125 * ( qu[i]·K[j] + qu[i]·R[j-i] + rcorr[j-i] )
// thread (tx,ty): rows r = ty*4+i (i<4), cols c = tx + 16*cc (cc<2),
// output dims tx*4..tx*4+3.
// ---------------------------------------------------------------------------
__global__ __launch_bounds__(256) void attn_kernel(
    const float* __restrict__ q, const float* __restrict__ k,
    const float* __restrict__ v, const float* __restrict__ Rm,
    const float* __restrict__ rc, float* __restrict__ ctx)
{
    __shared__ float QU[64][68];
    __shared__ float KT[32][68];
    __shared__ float VT[32][68];
    __shared__ float RT[95][68];
    __shared__ float RC[95];

    const int tid = threadIdx.x;
    const int tx = tid & 15, ty = tid >> 4;
    const int i0 = blockIdx.x << 6;
    const int h = blockIdx.y, b = blockIdx.z;
    const size_t bh = (size_t)(b * NH + h) * SEQ * DH;
    const float* qbh = q + bh;
    const float* kbh = k + bh;
    const float* vbh = v + bh;
    const float* Rh  = Rm + (((size_t)h << 10) << 6);
    const float* rch = rc + ((size_t)h << 10);

    for (int idx = tid; idx < 64 * 16; idx += 256) {
        const int r = idx >> 4, dq = (idx & 15) << 2;
        *(f4*)&QU[r][dq] = *(const f4*)&qbh[((size_t)(i0 + r) << 6) + dq];
    }

    float m_r[4] = {-3e38f, -3e38f, -3e38f, -3e38f};
    float l_r[4] = {0.f, 0.f, 0.f, 0.f};
    float o[4][4] = {};
    const int crb = tx - (ty << 2);   // (c - r) for cc=0, i=0

    for (int jt = 0; jt < 16; ++jt) {
        const int j0 = jt << 5;
        const int base = j0 - i0 + 448;   // dd for RT row 0
        __syncthreads();
        for (int idx = tid; idx < 32 * 16; idx += 256) {
            const int r = idx >> 4, dq = (idx & 15) << 2;
            *(f4*)&KT[r][dq] = *(const f4*)&kbh[((size_t)(j0 + r) << 6) + dq];
            *(f4*)&VT[r][dq] = *(const f4*)&vbh[((size_t)(j0 + r) << 6) + dq];
        }
        for (int idx = tid; idx < 95 * 16; idx += 256) {
            const int r = idx >> 4, dq = (idx & 15) << 2;
            *(f4*)&RT[r][dq] = *(const f4*)&Rh[((size_t)(base + r) << 6) + dq];
        }
        if (tid < 95) RC[tid] = rch[base + tid];
        __syncthreads();

        float sc[4][2] = {};
#pragma unroll
        for (int dq = 0; dq < 16; ++dq) {
            const int d4 = dq << 2;
            const f4 kv0 = *(const f4*)&KT[tx][d4];
            const f4 kv1 = *(const f4*)&KT[tx + 16][d4];
            f4 rt0[4], rt1[4];
#pragma unroll
            for (int t = 0; t < 4; ++t) {
                rt0[t] = *(const f4*)&RT[60 + crb + t][d4];
                rt1[t] = *(const f4*)&RT[76 + crb + t][d4];
            }
#pragma unroll
            for (int i = 0; i < 4; ++i) {
                const f4 a = *(const f4*)&QU[(ty << 2) + i][d4];
                sc[i][0] = dot4(a, kv0, sc[i][0]);
                sc[i][0] = dot4(a, rt0[3 - i], sc[i][0]);
                sc[i][1] = dot4(a, kv1, sc[i][1]);
                sc[i][1] = dot4(a, rt1[3 - i], sc[i][1]);
            }
        }

        // online softmax update (row reductions across the 16 tx lanes)
#pragma unroll
        for (int i = 0; i < 4; ++i) {
            const int ci0 = 63 + crb - i;
            float s0 = (sc[i][0] + RC[ci0]) * 0.125f;
            float s1 = (sc[i][1] + RC[ci0 + 16]) * 0.125f;
            float mt = fmaxf(s0, s1);
#pragma unroll
            for (int off = 8; off; off >>= 1) mt = fmaxf(mt, __shfl_xor(mt, off, 16));
            const float mn = fmaxf(m_r[i], mt);
            const float alpha = __expf(m_r[i] - mn);
            m_r[i] = mn;
            const float p0 = __expf(s0 - mn);
            const float p1 = __expf(s1 - mn);
            sc[i][0] = p0; sc[i][1] = p1;
            float rs = p0 + p1;
#pragma unroll
            for (int off = 8; off; off >>= 1) rs += __shfl_xor(rs, off, 16);
            l_r[i] = fmaf(l_r[i], alpha, rs);
            o[i][0] *= alpha; o[i][1] *= alpha; o[i][2] *= alpha; o[i][3] *= alpha;
        }

        // PV: broadcast p across the 16-lane row group, accumulate o
#pragma unroll
        for (int lx = 0; lx < 16; ++lx) {
#pragma unroll
            for (int cc = 0; cc < 2; ++cc) {
                const f4 vv = *(const f4*)&VT[lx + (cc << 4)][tx << 2];
#pragma unroll
                for (int i = 0; i < 4; ++i) {
                    const float pv = __shfl(sc[i][cc], lx, 16);
                    o[i][0] = fmaf(pv, vv.x, o[i][0]);
                    o[i][1] = fmaf(pv, vv.y, o[i][1]);
                    o[i][2] = fmaf(pv, vv.z, o[i][2]);
                    o[i][3] = fmaf(pv, vv.w, o[i][3]);
                }
            }
        }
    }

    // normalize + store ctx[b][s][h*64 + dims]
#pragma unroll
    for (int i = 0; i < 4; ++i) {
        const int s = i0 + (ty << 2) + i;
        const float inv = 1.f / l_r[i];
        f4 res = {o[i][0] * inv, o[i][1] * inv, o[i][2] * inv, o[i][3] * inv};
        *(f4*)&ctx[((size_t)b * SEQ + s) * DM + (h << 6) + (tx << 2)] = res;
    }
}

extern "C" void kernel_launch(void* const* d_in, const int* in_sizes, int n_in,
                              void* d_out, int out_size, void* d_ws, size_t ws_size,
                              hipStream_t stream)
{
    const float* x  = (const float*)d_in[0];
    const float* wq = (const float*)d_in[1];
    const float* bq = (const float*)d_in[2];
    const float* wk = (const float*)d_in[3];
    const float* bk = (const float*)d_in[4];
    const float* wv = (const float*)d_in[5];
    const float* bv = (const float*)d_in[6];
    const float* wo = (const float*)d_in[7];
    const float* bo = (const float*)d_in[8];
    const float* wr = (const float*)d_in[9];
    const float* u  = (const float*)d_in[10];
    const float* vb = (const float*)d_in[11];
    const float* pe = (const float*)d_in[12];
    float* out = (float*)d_out;
    float* ws  = (float*)d_ws;

    float* q   = ws;                  // [B,H,S,dh]  8 MB (includes +u +bq)
    float* kk  = ws + 2097152;        // [B,H,S,dh]  8 MB
    float* vv  = ws + 4194304;        // [B,H,S,dh]  8 MB
    float* Rm  = ws + 6291456;        // [H,1024,dh] 2 MB
    float* rc  = ws + 6815744;        // [H,1024]    32 KB
    float* ctx = ws + 6823936;        // [B,S,D]     8 MB

    dim3 blk(256);
    gemm_kernel<0><<<dim3(8, 64), blk, 0, stream>>>(x, wq, bq, u, q);
    gemm_kernel<0><<<dim3(8, 64), blk, 0, stream>>>(x, wk, bk, nullptr, kk);
    gemm_kernel<0><<<dim3(8, 64), blk, 0, stream>>>(x, wv, bv, nullptr, vv);
    gemm_kernel<1><<<dim3(8, 16), blk, 0, stream>>>(pe + (size_t)PE_OFF * DM, wr,
                                                    nullptr, nullptr, Rm);
    corr_kernel<<<dim3(16, 8), dim3(64), 0, stream>>>(Rm, u, vb, rc);
    attn_kernel<<<dim3(8, 8, 8), blk, 0, stream>>>(q, kk, vv, Rm, rc, ctx);
    gemm_kernel<2><<<dim3(8, 64), blk, 0, stream>>>(ctx, wo, bo, nullptr, out);
}

// Round 2
// 256.997 us; speedup vs baseline: 1.2897x; 1.2897x over previous
//
#include <hip/hip_runtime.h>
#include <math.h>

#define DM 512
#define NH 8
#define DH 64
#define SEQ 512
#define BATCH 8
#define MR 1023          // distinct relative offsets: 2*SEQ-1
#define PE_OFF 4489      // pe row for dd=0: (0-511)+5000

typedef float4 f4;
typedef __attribute__((ext_vector_type(8))) short bf16x8;
typedef __attribute__((ext_vector_type(4))) float f32x4;
typedef __attribute__((ext_vector_type(8))) unsigned short u16x8;

__device__ __forceinline__ unsigned short f2bf(float f) {
    unsigned x = __float_as_uint(f);
    unsigned r = x + 0x7fffu + ((x >> 16) & 1u);
    return (unsigned short)(r >> 16);
}
__device__ __forceinline__ float bf2f(unsigned short h) {
    return __uint_as_float(((unsigned)h) << 16);
}

__device__ __forceinline__ float dot4(f4 a, f4 b, float acc) {
    acc = fmaf(a.x, b.x, acc);
    acc = fmaf(a.y, b.y, acc);
    acc = fmaf(a.z, b.z, acc);
    acc = fmaf(a.w, b.w, acc);
    return acc;
}

__device__ __forceinline__ f32x4 mfma16(bf16x8 a, bf16x8 b, f32x4 c) {
    return __builtin_amdgcn_mfma_f32_16x16x32_bf16(a, b, c, 0, 0, 0);
}

// ---------------------------------------------------------------------------
// fp32 -> (bf16 hi, bf16 lo) split conversion, 8 elems/thread
// ---------------------------------------------------------------------------
__device__ __forceinline__ void cvt8(const float* __restrict__ src,
                                     unsigned short* __restrict__ hi,
                                     unsigned short* __restrict__ lo, int i) {
    f4 a = *(const f4*)&src[i];
    f4 b = *(const f4*)&src[i + 4];
    float v[8] = {a.x, a.y, a.z, a.w, b.x, b.y, b.z, b.w};
    u16x8 h, l;
#pragma unroll
    for (int j = 0; j < 8; ++j) {
        unsigned short hb = f2bf(v[j]);
        h[j] = hb;
        l[j] = f2bf(v[j] - bf2f(hb));
    }
    *(u16x8*)&hi[i] = h;
    *(u16x8*)&lo[i] = l;
}

__global__ __launch_bounds__(256) void cvt_kernel(const float* __restrict__ src,
    unsigned short* __restrict__ hi, unsigned short* __restrict__ lo, int n)
{
    const int i = (blockIdx.x * 256 + threadIdx.x) * 8;
    if (i >= n) return;
    cvt8(src, hi, lo, i);
}

// 5 weight matrices [512,512] each -> hi/lo pairs at bfbase+4194304 + y*524288
__global__ __launch_bounds__(256) void cvt_w_kernel(
    const float* __restrict__ w0, const float* __restrict__ w1,
    const float* __restrict__ w2, const float* __restrict__ w3,
    const float* __restrict__ w4, unsigned short* __restrict__ bfbase)
{
    const float* src = (blockIdx.y == 0) ? w0 : (blockIdx.y == 1) ? w1 :
                       (blockIdx.y == 2) ? w2 : (blockIdx.y == 3) ? w3 : w4;
    unsigned short* hi = bfbase + 4194304 + (size_t)blockIdx.y * 524288;
    unsigned short* lo = hi + 262144;
    const int i = (blockIdx.x * 256 + threadIdx.x) * 8;
    cvt8(src, hi, lo, i);
}

// ---------------------------------------------------------------------------
// Split-bf16 MFMA GEMM: C = A[M,512] @ W[512,512]^T (+bias[+bias2])
// A,W given as bf16 hi/lo pairs. 64x64 tile, 4 waves (each 32x32 = 2x2 frags),
// BK=32, 16x16x32 MFMA, 3 MFMAs per frag per k-step (hh + hl + lh).
// MODE 0: scatter to [B,H,S,dh]; MODE 1: Rm[h][dd][dh], guard dd<1023;
// MODE 2: row-major [M,512] + bias.
// ---------------------------------------------------------------------------
template<int MODE>
__global__ __launch_bounds__(256) void gemm_bf16s(
    const unsigned short* __restrict__ Ah, const unsigned short* __restrict__ Al,
    const unsigned short* __restrict__ Wh, const unsigned short* __restrict__ Wl,
    const float* __restrict__ bias, const float* __restrict__ bias2,
    float* __restrict__ C)
{
    // rows padded to 40 ushorts (80B): 16B-aligned, 2-way-max bank aliasing
    __shared__ unsigned short LAh[64][40], LAl[64][40], LBh[64][40], LBl[64][40];

    const int tid = threadIdx.x;
    const int lane = tid & 63;
    const int wid = tid >> 6;
    const int m0 = blockIdx.y << 6, n0 = blockIdx.x << 6;
    const int wm = (wid >> 1) << 5, wn = (wid & 1) << 5;
    const int sr = tid >> 2, sc = (tid & 3) << 3;   // staging: row, k-col*8
    const int fr = lane & 15, g = lane >> 4;        // fragment: row/col, k-group

    f32x4 acc[2][2];
#pragma unroll
    for (int i = 0; i < 2; ++i)
#pragma unroll
        for (int j = 0; j < 2; ++j)
            acc[i][j] = (f32x4){0.f, 0.f, 0.f, 0.f};

    const size_t arow = (size_t)(m0 + sr) * DM + sc;
    const size_t wrow = (size_t)(n0 + sr) * DM + sc;

    for (int k0 = 0; k0 < DM; k0 += 32) {
        u16x8 va_h = *(const u16x8*)&Ah[arow + k0];
        u16x8 va_l = *(const u16x8*)&Al[arow + k0];
        u16x8 vb_h = *(const u16x8*)&Wh[wrow + k0];
        u16x8 vb_l = *(const u16x8*)&Wl[wrow + k0];
        if (k0) __syncthreads();
        *(u16x8*)&LAh[sr][sc] = va_h;
        *(u16x8*)&LAl[sr][sc] = va_l;
        *(u16x8*)&LBh[sr][sc] = vb_h;
        *(u16x8*)&LBl[sr][sc] = vb_l;
        __syncthreads();

        bf16x8 a_h[2], a_l[2], b_h[2], b_l[2];
#pragma unroll
        for (int mi = 0; mi < 2; ++mi) {
            a_h[mi] = *(const bf16x8*)&LAh[wm + (mi << 4) + fr][g << 3];
            a_l[mi] = *(const bf16x8*)&LAl[wm + (mi << 4) + fr][g << 3];
        }
#pragma unroll
        for (int ni = 0; ni < 2; ++ni) {
            b_h[ni] = *(const bf16x8*)&LBh[wn + (ni << 4) + fr][g << 3];
            b_l[ni] = *(const bf16x8*)&LBl[wn + (ni << 4) + fr][g << 3];
        }
#pragma unroll
        for (int mi = 0; mi < 2; ++mi)
#pragma unroll
            for (int ni = 0; ni < 2; ++ni) {
                acc[mi][ni] = mfma16(a_h[mi], b_h[ni], acc[mi][ni]);
                acc[mi][ni] = mfma16(a_h[mi], b_l[ni], acc[mi][ni]);
                acc[mi][ni] = mfma16(a_l[mi], b_h[ni], acc[mi][ni]);
            }
    }

    // epilogue: C frag layout col = lane&15, row = (lane>>4)*4 + reg  [m89]
#pragma unroll
    for (int ni = 0; ni < 2; ++ni) {
        const int n_g = n0 + wn + (ni << 4) + fr;
        float bv = 0.f;
        if (MODE != 1) {
            bv = bias ? bias[n_g] : 0.f;
            if (MODE == 0 && bias2) bv += bias2[n_g];
        }
#pragma unroll
        for (int mi = 0; mi < 2; ++mi) {
#pragma unroll
            for (int r = 0; r < 4; ++r) {
                const int m_g = m0 + wm + (mi << 4) + (g << 2) + r;
                const float val = acc[mi][ni][r] + bv;
                if (MODE == 0) {
                    const int b = m_g >> 9, s = m_g & 511;
                    const int h = n_g >> 6, d = n_g & 63;
                    C[(((size_t)(b * NH + h) * SEQ + s) << 6) + d] = val;
                } else if (MODE == 1) {
                    if (m_g < MR) {
                        const int h = n_g >> 6, d = n_g & 63;
                        C[((((size_t)h << 10) + m_g) << 6) + d] = val;
                    }
                } else {
                    C[(size_t)m_g * DM + n_g] = val;
                }
            }
        }
    }
}

// rcorr[h][dd] = sum_d (v_bias[h,d] - u[h,d]) * Rm[h][dd][d]
__global__ __launch_bounds__(64) void corr_kernel(
    const float* __restrict__ Rm, const float* __restrict__ u,
    const float* __restrict__ vb, float* __restrict__ rc)
{
    const int h = blockIdx.y;
    const int dd = (blockIdx.x << 6) + threadIdx.x;
    float s = 0.f;
    if (dd < MR) {
        const float* r  = Rm + ((((size_t)h << 10) + dd) << 6);
        const float* uu = u + h * DH;
        const float* vv = vb + h * DH;
        for (int d = 0; d < DH; ++d) s = fmaf(vv[d] - uu[d], r[d], s);
    }
    rc[((size_t)h << 10) + dd] = s;
}

// ---------------------------------------------------------------------------
// Flash attention with relative position term (fp32, unchanged from R0).
// ---------------------------------------------------------------------------
__global__ __launch_bounds__(256) void attn_kernel(
    const float* __restrict__ q, const float* __restrict__ k,
    const float* __restrict__ v, const float* __restrict__ Rm,
    const float* __restrict__ rc, float* __restrict__ ctx)
{
    __shared__ float QU[64][68];
    __shared__ float KT[32][68];
    __shared__ float VT[32][68];
    __shared__ float RT[95][68];
    __shared__ float RC[95];

    const int tid = threadIdx.x;
    const int tx = tid & 15, ty = tid >> 4;
    const int i0 = blockIdx.x << 6;
    const int h = blockIdx.y, b = blockIdx.z;
    const size_t bh = (size_t)(b * NH + h) * SEQ * DH;
    const float* qbh = q + bh;
    const float* kbh = k + bh;
    const float* vbh = v + bh;
    const float* Rh  = Rm + (((size_t)h << 10) << 6);
    const float* rch = rc + ((size_t)h << 10);

    for (int idx = tid; idx < 64 * 16; idx += 256) {
        const int r = idx >> 4, dq = (idx & 15) << 2;
        *(f4*)&QU[r][dq] = *(const f4*)&qbh[((size_t)(i0 + r) << 6) + dq];
    }

    float m_r[4] = {-3e38f, -3e38f, -3e38f, -3e38f};
    float l_r[4] = {0.f, 0.f, 0.f, 0.f};
    float o[4][4] = {};
    const int crb = tx - (ty << 2);

    for (int jt = 0; jt < 16; ++jt) {
        const int j0 = jt << 5;
        const int base = j0 - i0 + 448;
        __syncthreads();
        for (int idx = tid; idx < 32 * 16; idx += 256) {
            const int r = idx >> 4, dq = (idx & 15) << 2;
            *(f4*)&KT[r][dq] = *(const f4*)&kbh[((size_t)(j0 + r) << 6) + dq];
            *(f4*)&VT[r][dq] = *(const f4*)&vbh[((size_t)(j0 + r) << 6) + dq];
        }
        for (int idx = tid; idx < 95 * 16; idx += 256) {
            const int r = idx >> 4, dq = (idx & 15) << 2;
            *(f4*)&RT[r][dq] = *(const f4*)&Rh[((size_t)(base + r) << 6) + dq];
        }
        if (tid < 95) RC[tid] = rch[base + tid];
        __syncthreads();

        float sc[4][2] = {};
#pragma unroll
        for (int dq = 0; dq < 16; ++dq) {
            const int d4 = dq << 2;
            const f4 kv0 = *(const f4*)&KT[tx][d4];
            const f4 kv1 = *(const f4*)&KT[tx + 16][d4];
            f4 rt0[4], rt1[4];
#pragma unroll
            for (int t = 0; t < 4; ++t) {
                rt0[t] = *(const f4*)&RT[60 + crb + t][d4];
                rt1[t] = *(const f4*)&RT[76 + crb + t][d4];
            }
#pragma unroll
            for (int i = 0; i < 4; ++i) {
                const f4 a = *(const f4*)&QU[(ty << 2) + i][d4];
                sc[i][0] = dot4(a, kv0, sc[i][0]);
                sc[i][0] = dot4(a, rt0[3 - i], sc[i][0]);
                sc[i][1] = dot4(a, kv1, sc[i][1]);
                sc[i][1] = dot4(a, rt1[3 - i], sc[i][1]);
            }
        }

#pragma unroll
        for (int i = 0; i < 4; ++i) {
            const int ci0 = 63 + crb - i;
            float s0 = (sc[i][0] + RC[ci0]) * 0.125f;
            float s1 = (sc[i][1] + RC[ci0 + 16]) * 0.125f;
            float mt = fmaxf(s0, s1);
#pragma unroll
            for (int off = 8; off; off >>= 1) mt = fmaxf(mt, __shfl_xor(mt, off, 16));
            const float mn = fmaxf(m_r[i], mt);
            const float alpha = __expf(m_r[i] - mn);
            m_r[i] = mn;
            const float p0 = __expf(s0 - mn);
            const float p1 = __expf(s1 - mn);
            sc[i][0] = p0; sc[i][1] = p1;
            float rs = p0 + p1;
#pragma unroll
            for (int off = 8; off; off >>= 1) rs += __shfl_xor(rs, off, 16);
            l_r[i] = fmaf(l_r[i], alpha, rs);
            o[i][0] *= alpha; o[i][1] *= alpha; o[i][2] *= alpha; o[i][3] *= alpha;
        }

#pragma unroll
        for (int lx = 0; lx < 16; ++lx) {
#pragma unroll
            for (int cc = 0; cc < 2; ++cc) {
                const f4 vv = *(const f4*)&VT[lx + (cc << 4)][tx << 2];
#pragma unroll
                for (int i = 0; i < 4; ++i) {
                    const float pv = __shfl(sc[i][cc], lx, 16);
                    o[i][0] = fmaf(pv, vv.x, o[i][0]);
                    o[i][1] = fmaf(pv, vv.y, o[i][1]);
                    o[i][2] = fmaf(pv, vv.z, o[i][2]);
                    o[i][3] = fmaf(pv, vv.w, o[i][3]);
                }
            }
        }
    }

#pragma unroll
    for (int i = 0; i < 4; ++i) {
        const int s = i0 + (ty << 2) + i;
        const float inv = 1.f / l_r[i];
        f4 res = {o[i][0] * inv, o[i][1] * inv, o[i][2] * inv, o[i][3] * inv};
        *(f4*)&ctx[((size_t)b * SEQ + s) * DM + (h << 6) + (tx << 2)] = res;
    }
}

extern "C" void kernel_launch(void* const* d_in, const int* in_sizes, int n_in,
                              void* d_out, int out_size, void* d_ws, size_t ws_size,
                              hipStream_t stream)
{
    const float* x  = (const float*)d_in[0];
    const float* wq = (const float*)d_in[1];
    const float* bq = (const float*)d_in[2];
    const float* wk = (const float*)d_in[3];
    const float* bk = (const float*)d_in[4];
    const float* wv = (const float*)d_in[5];
    const float* bv = (const float*)d_in[6];
    const float* wo = (const float*)d_in[7];
    const float* bo = (const float*)d_in[8];
    const float* wr = (const float*)d_in[9];
    const float* u  = (const float*)d_in[10];
    const float* vb = (const float*)d_in[11];
    const float* pe = (const float*)d_in[12];
    float* out = (float*)d_out;
    float* ws  = (float*)d_ws;

    float* q   = ws;                  // [B,H,S,dh]  8 MB
    float* kk  = ws + 2097152;        // [B,H,S,dh]  8 MB
    float* vv  = ws + 4194304;        // [B,H,S,dh]  8 MB
    float* Rm  = ws + 6291456;        // [H,1024,dh] 2 MB
    float* rc  = ws + 6815744;        // [H,1024]    32 KB
    float* ctx = ws + 6823936;        // [B,S,D]     8 MB

    // bf16 hi/lo region (ushort elems), ~15.7 MB
    unsigned short* bf  = (unsigned short*)(ws + 8921088);
    unsigned short* xh  = bf;                       // 2097152
    unsigned short* xl  = bf + 2097152;
    unsigned short* wqh = bf + 4194304;             // 5 weights, hi+lo pairs
    unsigned short* wql = wqh + 262144;
    unsigned short* wkh = wqh + 524288;
    unsigned short* wkl = wkh + 262144;
    unsigned short* wvh = wqh + 1048576;
    unsigned short* wvl = wvh + 262144;
    unsigned short* woh = wqh + 1572864;
    unsigned short* wol = woh + 262144;
    unsigned short* wrh = wqh + 2097152;
    unsigned short* wrl = wrh + 262144;
    unsigned short* peh = bf + 6815744;             // 523776
    unsigned short* pel = bf + 7339520;             // 523776
    unsigned short* cth = xh;                       // reuse x's slots for ctx
    unsigned short* ctl = xl;

    dim3 blk(256);
    cvt_kernel<<<1024, blk, 0, stream>>>(x, xh, xl, 2097152);
    cvt_w_kernel<<<dim3(128, 5), blk, 0, stream>>>(wq, wk, wv, wo, wr, bf);
    cvt_kernel<<<256, blk, 0, stream>>>(pe + (size_t)PE_OFF * DM, peh, pel, 523776);

    gemm_bf16s<0><<<dim3(8, 64), blk, 0, stream>>>(xh, xl, wqh, wql, bq, u, q);
    gemm_bf16s<0><<<dim3(8, 64), blk, 0, stream>>>(xh, xl, wkh, wkl, bk, nullptr, kk);
    gemm_bf16s<0><<<dim3(8, 64), blk, 0, stream>>>(xh, xl, wvh, wvl, bv, nullptr, vv);
    gemm_bf16s<1><<<dim3(8, 16), blk, 0, stream>>>(peh, pel, wrh, wrl, nullptr, nullptr, Rm);
    corr_kernel<<<dim3(16, 8), dim3(64), 0, stream>>>(Rm, u, vb, rc);
    attn_kernel<<<dim3(8, 8, 8), blk, 0, stream>>>(q, kk, vv, Rm, rc, ctx);
    cvt_kernel<<<1024, blk, 0, stream>>>(ctx, cth, ctl, 2097152);
    gemm_bf16s<2><<<dim3(8, 64), blk, 0, stream>>>(cth, ctl, woh, wol, bo, nullptr, out);
}

// Round 3
// 161.773 us; speedup vs baseline: 2.0488x; 1.5886x over previous
//
#include <hip/hip_runtime.h>
#include <math.h>

#define DM 512
#define NH 8
#define DH 64
#define SEQ 512
#define BATCH 8
#define MR 1023
#define PE_OFF 4489

typedef float4 f4;
typedef __attribute__((ext_vector_type(8))) short bf16x8;
typedef __attribute__((ext_vector_type(4))) float f32x4;
typedef __attribute__((ext_vector_type(8))) unsigned short u16x8;
typedef __attribute__((ext_vector_type(4))) unsigned short u16x4;

__device__ __forceinline__ unsigned short f2bf(float f) {
    unsigned x = __float_as_uint(f);
    unsigned r = x + 0x7fffu + ((x >> 16) & 1u);
    return (unsigned short)(r >> 16);
}
__device__ __forceinline__ float bf2f(unsigned short h) {
    return __uint_as_float(((unsigned)h) << 16);
}
__device__ __forceinline__ f32x4 mfma16(bf16x8 a, bf16x8 b, f32x4 c) {
    return __builtin_amdgcn_mfma_f32_16x16x32_bf16(a, b, c, 0, 0, 0);
}

// ---------------------------------------------------------------------------
// fp32 -> (bf16 hi, bf16 lo) split conversion
// ---------------------------------------------------------------------------
__device__ __forceinline__ void cvt8(const float* __restrict__ src,
                                     unsigned short* __restrict__ hi,
                                     unsigned short* __restrict__ lo, int i) {
    f4 a = *(const f4*)&src[i];
    f4 b = *(const f4*)&src[i + 4];
    float v[8] = {a.x, a.y, a.z, a.w, b.x, b.y, b.z, b.w};
    u16x8 h, l;
#pragma unroll
    for (int j = 0; j < 8; ++j) {
        unsigned short hb = f2bf(v[j]);
        h[j] = hb;
        l[j] = f2bf(v[j] - bf2f(hb));
    }
    *(u16x8*)&hi[i] = h;
    *(u16x8*)&lo[i] = l;
}

__global__ __launch_bounds__(256) void cvt_kernel(const float* __restrict__ src,
    unsigned short* __restrict__ hi, unsigned short* __restrict__ lo, int n)
{
    const int i = (blockIdx.x * 256 + threadIdx.x) * 8;
    if (i >= n) return;
    cvt8(src, hi, lo, i);
}

__global__ __launch_bounds__(256) void cvt_w_kernel(
    const float* __restrict__ w0, const float* __restrict__ w1,
    const float* __restrict__ w2, const float* __restrict__ w3,
    const float* __restrict__ w4, unsigned short* __restrict__ wb)
{
    const float* src = (blockIdx.y == 0) ? w0 : (blockIdx.y == 1) ? w1 :
                       (blockIdx.y == 2) ? w2 : (blockIdx.y == 3) ? w3 : w4;
    unsigned short* hi = wb + (size_t)blockIdx.y * 524288;
    unsigned short* lo = hi + 262144;
    const int i = (blockIdx.x * 256 + threadIdx.x) * 8;
    cvt8(src, hi, lo, i);
}

// ---------------------------------------------------------------------------
// Shared split-bf16 GEMM core: 64x64 tile, acc[2][2] of 16x16 frags per wave.
// ---------------------------------------------------------------------------
__device__ __forceinline__ void gemm_core(
    const unsigned short* __restrict__ Ah, const unsigned short* __restrict__ Al,
    const unsigned short* __restrict__ Wh, const unsigned short* __restrict__ Wl,
    int m0, int n0, f32x4 acc[2][2],
    unsigned short* LAh, unsigned short* LAl,
    unsigned short* LBh, unsigned short* LBl)
{
    const int tid = threadIdx.x;
    const int lane = tid & 63, wid = tid >> 6;
    const int wm = (wid >> 1) << 5, wn = (wid & 1) << 5;
    const int sr = tid >> 2, sc = (tid & 3) << 3;
    const int fr = lane & 15, g = lane >> 4;

#pragma unroll
    for (int i = 0; i < 2; ++i)
#pragma unroll
        for (int j = 0; j < 2; ++j)
            acc[i][j] = (f32x4){0.f, 0.f, 0.f, 0.f};

    const size_t arow = (size_t)(m0 + sr) * DM + sc;
    const size_t wrow = (size_t)(n0 + sr) * DM + sc;

    for (int k0 = 0; k0 < DM; k0 += 32) {
        u16x8 va_h = *(const u16x8*)&Ah[arow + k0];
        u16x8 va_l = *(const u16x8*)&Al[arow + k0];
        u16x8 vb_h = *(const u16x8*)&Wh[wrow + k0];
        u16x8 vb_l = *(const u16x8*)&Wl[wrow + k0];
        if (k0) __syncthreads();
        *(u16x8*)&LAh[sr * 40 + sc] = va_h;
        *(u16x8*)&LAl[sr * 40 + sc] = va_l;
        *(u16x8*)&LBh[sr * 40 + sc] = vb_h;
        *(u16x8*)&LBl[sr * 40 + sc] = vb_l;
        __syncthreads();

        bf16x8 a_h[2], a_l[2], b_h[2], b_l[2];
#pragma unroll
        for (int mi = 0; mi < 2; ++mi) {
            a_h[mi] = *(const bf16x8*)&LAh[(wm + (mi << 4) + fr) * 40 + (g << 3)];
            a_l[mi] = *(const bf16x8*)&LAl[(wm + (mi << 4) + fr) * 40 + (g << 3)];
        }
#pragma unroll
        for (int ni = 0; ni < 2; ++ni) {
            b_h[ni] = *(const bf16x8*)&LBh[(wn + (ni << 4) + fr) * 40 + (g << 3)];
            b_l[ni] = *(const bf16x8*)&LBl[(wn + (ni << 4) + fr) * 40 + (g << 3)];
        }
#pragma unroll
        for (int mi = 0; mi < 2; ++mi)
#pragma unroll
            for (int ni = 0; ni < 2; ++ni) {
                acc[mi][ni] = mfma16(a_h[mi], b_h[ni], acc[mi][ni]);
                acc[mi][ni] = mfma16(a_h[mi], b_l[ni], acc[mi][ni]);
                acc[mi][ni] = mfma16(a_l[mi], b_h[ni], acc[mi][ni]);
            }
    }
}

// ---------------------------------------------------------------------------
// Fused QKV projection. grid (24, 64): wsel = bx>>3 in {q,k,v}.
// q,k -> hi/lo [B,H,S,dh]; v -> hi/lo TRANSPOSED [B,H,dh,S].
// ---------------------------------------------------------------------------
__global__ __launch_bounds__(256) void qkv_kernel(
    const unsigned short* __restrict__ xh, const unsigned short* __restrict__ xl,
    const unsigned short* __restrict__ wb,
    const float* __restrict__ bq, const float* __restrict__ bk,
    const float* __restrict__ bv, const float* __restrict__ u,
    unsigned short* __restrict__ qh, unsigned short* __restrict__ ql,
    unsigned short* __restrict__ kh, unsigned short* __restrict__ kl,
    unsigned short* __restrict__ vth, unsigned short* __restrict__ vtl)
{
    __shared__ unsigned short LAh[64 * 40], LAl[64 * 40], LBh[64 * 40], LBl[64 * 40];
    const int wsel = blockIdx.x >> 3;
    const int n0 = (blockIdx.x & 7) << 6, m0 = blockIdx.y << 6;
    const unsigned short* Wh = wb + (size_t)wsel * 524288;
    const unsigned short* Wl = Wh + 262144;
    f32x4 acc[2][2];
    gemm_core(xh, xl, Wh, Wl, m0, n0, acc, LAh, LAl, LBh, LBl);

    const int tid = threadIdx.x, lane = tid & 63, wid = tid >> 6;
    const int wm = (wid >> 1) << 5, wn = (wid & 1) << 5;
    const int fr = lane & 15, g = lane >> 4;
    const float* bias = (wsel == 0) ? bq : (wsel == 1) ? bk : bv;

    if (wsel < 2) {
        unsigned short* oh = (wsel == 0) ? qh : kh;
        unsigned short* ol = (wsel == 0) ? ql : kl;
#pragma unroll
        for (int ni = 0; ni < 2; ++ni) {
            const int n_g = n0 + wn + (ni << 4) + fr;
            float bvv = bias[n_g] + ((wsel == 0) ? u[n_g] : 0.f);
            const int h = n_g >> 6, d = n_g & 63;
#pragma unroll
            for (int mi = 0; mi < 2; ++mi)
#pragma unroll
                for (int r = 0; r < 4; ++r) {
                    const int m_g = m0 + wm + (mi << 4) + (g << 2) + r;
                    const int b = m_g >> 9, s = m_g & 511;
                    const float val = acc[mi][ni][r] + bvv;
                    const size_t o = ((size_t)(b * NH + h) * SEQ + s) * DH + d;
                    const unsigned short hb = f2bf(val);
                    oh[o] = hb;
                    ol[o] = f2bf(val - bf2f(hb));
                }
        }
    } else {
#pragma unroll
        for (int ni = 0; ni < 2; ++ni) {
            const int n_g = n0 + wn + (ni << 4) + fr;
            const float bvv = bias[n_g];
            const int h = n_g >> 6, d = n_g & 63;
#pragma unroll
            for (int mi = 0; mi < 2; ++mi) {
                const int m_b = m0 + wm + (mi << 4) + (g << 2);
                const int b = m_b >> 9, s = m_b & 511;
                u16x4 hv, lv;
#pragma unroll
                for (int r = 0; r < 4; ++r) {
                    const float val = acc[mi][ni][r] + bvv;
                    hv[r] = f2bf(val);
                    lv[r] = f2bf(val - bf2f(hv[r]));
                }
                const size_t o = ((size_t)(b * NH + h) * DH + d) * SEQ + s;
                *(u16x4*)&vth[o] = hv;
                *(u16x4*)&vtl[o] = lv;
            }
        }
    }
}

// Rm[h][dd][d] hi/lo, dd in [0,1024)  (row 1023 garbage-but-finite, never used)
__global__ __launch_bounds__(256) void rm_kernel(
    const unsigned short* __restrict__ peh, const unsigned short* __restrict__ pel,
    const unsigned short* __restrict__ wrh, const unsigned short* __restrict__ wrl,
    unsigned short* __restrict__ rmh, unsigned short* __restrict__ rml)
{
    __shared__ unsigned short LAh[64 * 40], LAl[64 * 40], LBh[64 * 40], LBl[64 * 40];
    const int n0 = blockIdx.x << 6, m0 = blockIdx.y << 6;
    f32x4 acc[2][2];
    gemm_core(peh, pel, wrh, wrl, m0, n0, acc, LAh, LAl, LBh, LBl);

    const int tid = threadIdx.x, lane = tid & 63, wid = tid >> 6;
    const int wm = (wid >> 1) << 5, wn = (wid & 1) << 5;
    const int fr = lane & 15, g = lane >> 4;
#pragma unroll
    for (int ni = 0; ni < 2; ++ni) {
        const int n_g = n0 + wn + (ni << 4) + fr;
        const int h = n_g >> 6, d = n_g & 63;
#pragma unroll
        for (int mi = 0; mi < 2; ++mi)
#pragma unroll
            for (int r = 0; r < 4; ++r) {
                const int dd = m0 + wm + (mi << 4) + (g << 2) + r;
                const float val = acc[mi][ni][r];
                const size_t o = (((size_t)h << 10) + dd) * DH + d;
                const unsigned short hb = f2bf(val);
                rmh[o] = hb;
                rml[o] = f2bf(val - bf2f(hb));
            }
    }
}

// out = ctx @ wo^T + bo  (f32 out)
__global__ __launch_bounds__(256) void out_kernel(
    const unsigned short* __restrict__ cth, const unsigned short* __restrict__ ctl,
    const unsigned short* __restrict__ woh, const unsigned short* __restrict__ wol,
    const float* __restrict__ bo, float* __restrict__ out)
{
    __shared__ unsigned short LAh[64 * 40], LAl[64 * 40], LBh[64 * 40], LBl[64 * 40];
    const int n0 = blockIdx.x << 6, m0 = blockIdx.y << 6;
    f32x4 acc[2][2];
    gemm_core(cth, ctl, woh, wol, m0, n0, acc, LAh, LAl, LBh, LBl);

    const int tid = threadIdx.x, lane = tid & 63, wid = tid >> 6;
    const int wm = (wid >> 1) << 5, wn = (wid & 1) << 5;
    const int fr = lane & 15, g = lane >> 4;
#pragma unroll
    for (int ni = 0; ni < 2; ++ni) {
        const int n_g = n0 + wn + (ni << 4) + fr;
        const float bvv = bo[n_g];
#pragma unroll
        for (int mi = 0; mi < 2; ++mi)
#pragma unroll
            for (int r = 0; r < 4; ++r) {
                const int m_g = m0 + wm + (mi << 4) + (g << 2) + r;
                out[(size_t)m_g * DM + n_g] = acc[mi][ni][r] + bvv;
            }
    }
}

// rcorr[h][dd] = sum_d (v_bias - u) * Rm
__global__ __launch_bounds__(64) void corr_kernel(
    const unsigned short* __restrict__ rmh, const unsigned short* __restrict__ rml,
    const float* __restrict__ u, const float* __restrict__ vb,
    float* __restrict__ rc)
{
    const int h = blockIdx.y;
    const int dd = (blockIdx.x << 6) + threadIdx.x;
    float s = 0.f;
    if (dd < MR) {
        const size_t ro = (((size_t)h << 10) + dd) * DH;
        const float* uu = u + h * DH;
        const float* vv = vb + h * DH;
        for (int d = 0; d < DH; ++d)
            s = fmaf(vv[d] - uu[d], bf2f(rmh[ro + d]) + bf2f(rml[ro + d]), s);
    }
    rc[((size_t)h << 10) + dd] = s;
}

// ---------------------------------------------------------------------------
// MFMA flash attention. Block = (i-tile 64, h, b), 4 waves x 16 rows each.
// j-tiles of 64. score = 0.125*(qu.K[j] + qu.R[j-i] + rc[j-i])
// ---------------------------------------------------------------------------
__global__ __launch_bounds__(256) void attn_kernel(
    const unsigned short* __restrict__ qh_g, const unsigned short* __restrict__ ql_g,
    const unsigned short* __restrict__ kh_g, const unsigned short* __restrict__ kl_g,
    const unsigned short* __restrict__ vh_g, const unsigned short* __restrict__ vl_g,
    const unsigned short* __restrict__ rmh, const unsigned short* __restrict__ rml,
    const float* __restrict__ rc,
    unsigned short* __restrict__ cth, unsigned short* __restrict__ ctl)
{
    __shared__ unsigned short Kh[64][72], Kl[64][72], Vh[64][72], Vl[64][72];
    __shared__ unsigned short Pdd[4][16][84];   // wave-private, bf16(pos+rc)
    __shared__ float Pt[4][16][68];             // wave-private, P f32

    const int tid = threadIdx.x;
    const int lane = tid & 63, wid = tid >> 6;
    const int g = lane >> 4, c = lane & 15;
    const int i0 = blockIdx.x << 6;
    const int h = blockIdx.y, b = blockIdx.z;
    const int R0 = i0 + (wid << 4);
    const size_t bh = (size_t)(b * NH + h) * (SEQ * DH);

    // Q fragments hoisted (rows R0..R0+15)
    bf16x8 qhf[2], qlf[2];
#pragma unroll
    for (int ks = 0; ks < 2; ++ks) {
        const size_t qo = bh + (size_t)(R0 + c) * DH + (ks << 5) + (g << 3);
        qhf[ks] = *(const bf16x8*)&qh_g[qo];
        qlf[ks] = *(const bf16x8*)&ql_g[qo];
    }

    f32x4 Oacc[4];
#pragma unroll
    for (int nf = 0; nf < 4; ++nf) Oacc[nf] = (f32x4){0.f, 0.f, 0.f, 0.f};
    float m_r[4] = {-3e38f, -3e38f, -3e38f, -3e38f};
    float l_r[4] = {0.f, 0.f, 0.f, 0.f};

    const float* rch = rc + (h << 10);
    const unsigned short* rmhh = rmh + ((size_t)h << 16);
    const unsigned short* rmlh = rml + ((size_t)h << 16);

    for (int jt = 0; jt < 8; ++jt) {
        const int j0 = jt << 6;
        __syncthreads();
        // stage K hi/lo + Vt hi/lo (2048 16B-chunks, 8 per thread)
        for (int u_ = tid; u_ < 2048; u_ += 256) {
            const int arr = u_ >> 9, rem = u_ & 511, row = rem >> 3, ch = (rem & 7) << 3;
            u16x8 val;
            if (arr == 0)      val = *(const u16x8*)&kh_g[bh + (size_t)(j0 + row) * DH + ch];
            else if (arr == 1) val = *(const u16x8*)&kl_g[bh + (size_t)(j0 + row) * DH + ch];
            else if (arr == 2) val = *(const u16x8*)&vh_g[bh + (size_t)row * SEQ + j0 + ch];
            else               val = *(const u16x8*)&vl_g[bh + (size_t)row * SEQ + j0 + ch];
            unsigned short* dst = (arr == 0) ? &Kh[row][ch] : (arr == 1) ? &Kl[row][ch]
                                : (arr == 2) ? &Vh[row][ch] : &Vl[row][ch];
            *(u16x8*)dst = val;
        }
        __syncthreads();

        // content scores: acc_s[nf] over k=64
        f32x4 accs[4];
#pragma unroll
        for (int nf = 0; nf < 4; ++nf) accs[nf] = (f32x4){0.f, 0.f, 0.f, 0.f};
#pragma unroll
        for (int ks = 0; ks < 2; ++ks)
#pragma unroll
            for (int nf = 0; nf < 4; ++nf) {
                bf16x8 b_h = *(const bf16x8*)&Kh[(nf << 4) + c][(ks << 5) + (g << 3)];
                bf16x8 b_l = *(const bf16x8*)&Kl[(nf << 4) + c][(ks << 5) + (g << 3)];
                accs[nf] = mfma16(qhf[ks], b_h, accs[nf]);
                accs[nf] = mfma16(qhf[ks], b_l, accs[nf]);
                accs[nf] = mfma16(qlf[ks], b_h, accs[nf]);
            }

        // position dd-GEMM: Pdd[i][ddl] = qu[i].R[base+ddl] + rc, ddl in [0,80)
        const int base_g = j0 - R0 + 496;
        f32x4 accp[5];
#pragma unroll
        for (int f = 0; f < 5; ++f) accp[f] = (f32x4){0.f, 0.f, 0.f, 0.f};
#pragma unroll
        for (int ks = 0; ks < 2; ++ks)
#pragma unroll
            for (int f = 0; f < 5; ++f) {
                const size_t ro = (size_t)(base_g + (f << 4) + c) * DH + (ks << 5) + (g << 3);
                bf16x8 b_h = *(const bf16x8*)&rmhh[ro];
                bf16x8 b_l = *(const bf16x8*)&rmlh[ro];
                accp[f] = mfma16(qhf[ks], b_h, accp[f]);
                accp[f] = mfma16(qhf[ks], b_l, accp[f]);
                accp[f] = mfma16(qlf[ks], b_h, accp[f]);
            }
#pragma unroll
        for (int f = 0; f < 5; ++f) {
            const float rcv = rch[base_g + (f << 4) + c];
#pragma unroll
            for (int r = 0; r < 4; ++r)
                Pdd[wid][(g << 2) + r][(f << 4) + c] = f2bf(accp[f][r] + rcv);
        }

        // online softmax per row (gather Pdd at ddl = j - i + 15)
#pragma unroll
        for (int r = 0; r < 4; ++r) {
            const int irow = (g << 2) + r;
            float sc[4];
#pragma unroll
            for (int nf = 0; nf < 4; ++nf) {
                const int ddl = (nf << 4) + c - irow + 15;
                sc[nf] = (accs[nf][r] + bf2f(Pdd[wid][irow][ddl])) * 0.125f;
            }
            float mt = fmaxf(fmaxf(sc[0], sc[1]), fmaxf(sc[2], sc[3]));
#pragma unroll
            for (int off = 8; off; off >>= 1) mt = fmaxf(mt, __shfl_xor(mt, off, 16));
            const float mn = fmaxf(m_r[r], mt);
            const float alpha = __expf(m_r[r] - mn);
            m_r[r] = mn;
            float rs = 0.f;
#pragma unroll
            for (int nf = 0; nf < 4; ++nf) {
                const float p = __expf(sc[nf] - mn);
                Pt[wid][irow][(nf << 4) + c] = p;
                rs += p;
            }
#pragma unroll
            for (int off = 8; off; off >>= 1) rs += __shfl_xor(rs, off, 16);
            l_r[r] = l_r[r] * alpha + rs;
#pragma unroll
            for (int nf = 0; nf < 4; ++nf) Oacc[nf][r] *= alpha;
        }

        // PV: A = P (hi/lo from Pt), B = Vt
#pragma unroll
        for (int ks = 0; ks < 2; ++ks) {
            f4 p0 = *(const f4*)&Pt[wid][c][(ks << 5) + (g << 3)];
            f4 p1 = *(const f4*)&Pt[wid][c][(ks << 5) + (g << 3) + 4];
            float pv[8] = {p0.x, p0.y, p0.z, p0.w, p1.x, p1.y, p1.z, p1.w};
            bf16x8 ph, pl;
#pragma unroll
            for (int e = 0; e < 8; ++e) {
                const unsigned short hb = f2bf(pv[e]);
                ph[e] = (short)hb;
                pl[e] = (short)f2bf(pv[e] - bf2f(hb));
            }
#pragma unroll
            for (int nf = 0; nf < 4; ++nf) {
                bf16x8 v_h = *(const bf16x8*)&Vh[(nf << 4) + c][(ks << 5) + (g << 3)];
                bf16x8 v_l = *(const bf16x8*)&Vl[(nf << 4) + c][(ks << 5) + (g << 3)];
                Oacc[nf] = mfma16(ph, v_h, Oacc[nf]);
                Oacc[nf] = mfma16(ph, v_l, Oacc[nf]);
                Oacc[nf] = mfma16(pl, v_h, Oacc[nf]);
            }
        }
    }

    // epilogue: normalize, split hi/lo, store ctx[b][s][h*64+d]
    float inv[4];
#pragma unroll
    for (int r = 0; r < 4; ++r) inv[r] = 1.f / l_r[r];
#pragma unroll
    for (int nf = 0; nf < 4; ++nf)
#pragma unroll
        for (int r = 0; r < 4; ++r) {
            const float val = Oacc[nf][r] * inv[r];
            const int s = R0 + (g << 2) + r;
            const int d = (h << 6) + (nf << 4) + c;
            const size_t o = ((size_t)(b * SEQ) + s) * DM + d;
            const unsigned short hb = f2bf(val);
            cth[o] = hb;
            ctl[o] = f2bf(val - bf2f(hb));
        }
}

extern "C" void kernel_launch(void* const* d_in, const int* in_sizes, int n_in,
                              void* d_out, int out_size, void* d_ws, size_t ws_size,
                              hipStream_t stream)
{
    const float* x  = (const float*)d_in[0];
    const float* wq = (const float*)d_in[1];
    const float* bq = (const float*)d_in[2];
    const float* wk = (const float*)d_in[3];
    const float* bk = (const float*)d_in[4];
    const float* wv = (const float*)d_in[5];
    const float* bv = (const float*)d_in[6];
    const float* wo = (const float*)d_in[7];
    const float* bo = (const float*)d_in[8];
    const float* wr = (const float*)d_in[9];
    const float* u  = (const float*)d_in[10];
    const float* vb = (const float*)d_in[11];
    const float* pe = (const float*)d_in[12];
    float* out = (float*)d_out;
    unsigned short* us = (unsigned short*)d_ws;

    unsigned short* xh  = us;                    // 2097152
    unsigned short* xl  = us + 2097152;
    unsigned short* wb  = us + 4194304;          // 5 x (hi 262144 + lo 262144)
    unsigned short* peh = us + 6815744;          // 524288
    unsigned short* pel = us + 7340032;
    unsigned short* qh  = us + 7864320;          // 2097152 each
    unsigned short* ql  = us + 9961472;
    unsigned short* kh  = us + 12058624;
    unsigned short* kl  = us + 14155776;
    unsigned short* vth = us + 16252928;
    unsigned short* vtl = us + 18350080;
    unsigned short* rmh = us + 20447232;         // 524288 each
    unsigned short* rml = us + 20971520;
    unsigned short* cth = us + 21495808;
    unsigned short* ctl = us + 23592960;
    float* rc = (float*)(us + 25690112);         // 8192 f32

    unsigned short* woh = wb + 3 * 524288;
    unsigned short* wol = woh + 262144;
    unsigned short* wrh = wb + 4 * 524288;
    unsigned short* wrl = wrh + 262144;

    dim3 blk(256);
    cvt_kernel<<<1024, blk, 0, stream>>>(x, xh, xl, 2097152);
    cvt_w_kernel<<<dim3(128, 5), blk, 0, stream>>>(wq, wk, wv, wo, wr, wb);
    cvt_kernel<<<256, blk, 0, stream>>>(pe + (size_t)PE_OFF * DM, peh, pel, 523776);

    qkv_kernel<<<dim3(24, 64), blk, 0, stream>>>(xh, xl, wb, bq, bk, bv, u,
                                                 qh, ql, kh, kl, vth, vtl);
    rm_kernel<<<dim3(8, 16), blk, 0, stream>>>(peh, pel, wrh, wrl, rmh, rml);
    corr_kernel<<<dim3(16, 8), dim3(64), 0, stream>>>(rmh, rml, u, vb, rc);
    attn_kernel<<<dim3(8, 8, 8), blk, 0, stream>>>(qh, ql, kh, kl, vth, vtl,
                                                   rmh, rml, rc, cth, ctl);
    out_kernel<<<dim3(8, 64), blk, 0, stream>>>(cth, ctl, woh, wol, bo, out);
}